// Round 9
// baseline (216.755 us; speedup 1.0000x reference)
//
#include <hip/hip_runtime.h>
#include <math.h>

// Qnet: per-row tiny MLP + gumbel-sigmoid straight-through gates + 5 tiny experts.
//
// Round-8 post-mortem: no-LDS + s_load weights + e-domain got 123us
// (VALUBusy 51%, VGPR 64). Remaining: instruction-count overhead (46 mem
// instrs per 4 rows at 2-row/thread) + 33 quarter-rate trans/row.
// This round:
//   1. 4 rows/thread WITHOUT the round-6 spill: soft overwrites u1f's
//      register and hard overwrites u2f's at the consuming index (gate
//      (r,c) reads u[5r+c], writes soft/hard[5r+c]) -> ~82 live floats.
//      All loads/stores float4: x 4, u 5+5, out 2, soft/hard 5+5 = 26
//      mem instrs per 4 rows.
//   2. Un-divided e-domain: e' = exp(-lg)*(t1+eps); hard = (e' <= t2e);
//      soft = t2e * rcp(t2e + e')  [saves the per-gate divide-rcp + mul].
//      Flag window |e' - t2e| < 1.05e-4 * t2e (== |e/1 - 1| < 1.05e-4,
//      100x margin over ~1e-6 fast-path rel err; np dead band ~2e-7).
//   3. Weights via uniform-index global reads -> s_load/SGPR (scalar pipe).
// Rare flagged gates -> patch kernel = bit-exact CR-f32 numpy simulation
// (correctness authority near the boundary).

constexpr float EPSF = 1e-8f;

__device__ __forceinline__ float fast_tanh(float a) {
    const float ea = __expf(-2.0f * fabsf(a));
    const float r = (1.0f - ea) * __builtin_amdgcn_rcpf(1.0f + ea);
    return copysignf(r, a);
}

__global__ __launch_bounds__(256) void qnet_main(
    const float* __restrict__ x,
    const float* __restrict__ u1,
    const float* __restrict__ u2,
    const float* __restrict__ fc1_w,    // [4][4]
    const float* __restrict__ fc1_b,    // [4]
    const float* __restrict__ picker_w, // [5][4]
    const float* __restrict__ picker_b, // [5]
    const float* __restrict__ ew1,      // [5][4][4]
    const float* __restrict__ eb1,      // [5][4]
    const float* __restrict__ ew2,      // [5][2][4]
    const float* __restrict__ eb2,      // [5][2]
    float* __restrict__ out_o,          // [B][2]
    float* __restrict__ hard_o,         // [B][5]
    float* __restrict__ soft_o,         // [B][5]
    unsigned* __restrict__ flag_cnt,    // d_ws[0]
    unsigned* __restrict__ flag_list,   // d_ws[1..]
    unsigned flag_cap)
{
    const unsigned t = blockIdx.x * blockDim.x + threadIdx.x;  // rows 4t..4t+3

    const float4* x4  = reinterpret_cast<const float4*>(x);
    const float4* u14 = reinterpret_cast<const float4*>(u1);
    const float4* u24 = reinterpret_cast<const float4*>(u2);

    float xr[4][4];
#pragma unroll
    for (int r = 0; r < 4; ++r) {
        float4 v = x4[4u * t + r];
        xr[r][0] = v.x; xr[r][1] = v.y; xr[r][2] = v.z; xr[r][3] = v.w;
    }
    // us1 holds u1 values, then is overwritten in place by soft;
    // us2 holds u2 values, then is overwritten in place by hard.
    float us1[20], us2[20];
#pragma unroll
    for (int k = 0; k < 5; ++k) {
        float4 a = u14[5u * t + k];
        us1[4 * k + 0] = a.x; us1[4 * k + 1] = a.y; us1[4 * k + 2] = a.z; us1[4 * k + 3] = a.w;
        float4 b = u24[5u * t + k];
        us2[4 * k + 0] = b.x; us2[4 * k + 1] = b.y; us2[4 * k + 2] = b.z; us2[4 * k + 3] = b.w;
    }

    float outf[8];

#pragma unroll
    for (int r = 0; r < 4; ++r) {
        // h = tanh(fc1(x)) — weights at uniform indices (s_load/SGPR)
        float h[4];
#pragma unroll
        for (int j = 0; j < 4; ++j) {
            float a = fc1_b[j];
#pragma unroll
            for (int i = 0; i < 4; ++i) a += xr[r][i] * fc1_w[4 * j + i];
            h[j] = fast_tanh(a);
        }

        float o0 = 0.0f, o1 = 0.0f;
#pragma unroll
        for (int c = 0; c < 5; ++c) {
            float lg = picker_b[c];
#pragma unroll
            for (int j = 0; j < 4; ++j) lg += h[j] * picker_w[4 * c + j];

            const float uu1 = us1[5 * r + c];
            const float uu2 = us2[5 * r + c];
            const float t1e = -__logf(uu1 + EPSF) + EPSF;  // t1 + eps > 0
            const float t2e = -__logf(uu2 + EPSF) + EPSF;
            // e' = exp(-z)*(t2+eps) = exp(-lg)*(t1+eps)   [exact identity]
            const float ep = __expf(-lg) * t1e;
            const float sft = t2e * __builtin_amdgcn_rcpf(t2e + ep);
            const float hrd = (ep <= t2e) ? 1.0f : 0.0f;

            if (__builtin_expect(fabsf(ep - t2e) < 1.05e-4f * t2e, 0)) {
                const unsigned slot = atomicAdd(flag_cnt, 1u);
                if (slot < flag_cap)
                    flag_list[slot] = (((4u * t + r) * 5u + c) << 1) |
                                      (ep <= t2e ? 1u : 0u);
            }

            us1[5 * r + c] = sft;   // in-place: u1 -> soft
            us2[5 * r + c] = hrd;   // in-place: u2 -> hard

            // expert c: Linear(4,4)->ReLU->Linear(4,2)
            float eh[4];
#pragma unroll
            for (int k = 0; k < 4; ++k) {
                float a = eb1[4 * c + k];
#pragma unroll
                for (int j = 0; j < 4; ++j) a += h[j] * ew1[16 * c + 4 * k + j];
                eh[k] = fmaxf(a, 0.0f);
            }
            float e0 = eb2[2 * c + 0];
            float e1 = eb2[2 * c + 1];
#pragma unroll
            for (int k = 0; k < 4; ++k) {
                e0 += eh[k] * ew2[8 * c + 0 + k];
                e1 += eh[k] * ew2[8 * c + 4 + k];
            }
            o0 += hrd * e0;
            o1 += hrd * e1;
        }
        outf[2 * r + 0] = o0;
        outf[2 * r + 1] = o1;
    }

    float4* out4  = reinterpret_cast<float4*>(out_o);
    float4* soft4 = reinterpret_cast<float4*>(soft_o);
    float4* hard4 = reinterpret_cast<float4*>(hard_o);
    out4[2u * t + 0] = make_float4(outf[0], outf[1], outf[2], outf[3]);
    out4[2u * t + 1] = make_float4(outf[4], outf[5], outf[6], outf[7]);
#pragma unroll
    for (int k = 0; k < 5; ++k) {
        soft4[5u * t + k] = make_float4(us1[4 * k + 0], us1[4 * k + 1], us1[4 * k + 2], us1[4 * k + 3]);
        hard4[5u * t + k] = make_float4(us2[4 * k + 0], us2[4 * k + 1], us2[4 * k + 2], us2[4 * k + 3]);
    }
}

// ---- rare patch kernel: bit-exact CR-f32 numpy simulation (authority) ----
__global__ __launch_bounds__(256) void qnet_patch(
    const float* __restrict__ x,
    const float* __restrict__ u1,
    const float* __restrict__ u2,
    const float* __restrict__ fc1_w,
    const float* __restrict__ fc1_b,
    const float* __restrict__ picker_w,
    const float* __restrict__ picker_b,
    const float* __restrict__ ew1,
    const float* __restrict__ eb1,
    const float* __restrict__ ew2,
    const float* __restrict__ eb2,
    float* __restrict__ out_o,
    float* __restrict__ hard_o,
    float* __restrict__ soft_o,
    const unsigned* __restrict__ flag_cnt,
    const unsigned* __restrict__ flag_list,
    unsigned flag_cap)
{
    const unsigned n = min(flag_cnt[0], flag_cap);
    const unsigned stride = gridDim.x * blockDim.x;
    for (unsigned i = blockIdx.x * blockDim.x + threadIdx.x; i < n; i += stride) {
        const unsigned e = flag_list[i];
        const float fasthard = (e & 1u) ? 1.0f : 0.0f;
        const unsigned idx5 = e >> 1;
        const unsigned row = idx5 / 5u;
        const unsigned c = idx5 % 5u;

        const float4 xv = reinterpret_cast<const float4*>(x)[row];
        const float xr[4] = {xv.x, xv.y, xv.z, xv.w};
        const float uu1 = u1[idx5];
        const float uu2 = u2[idx5];

        float h32[4];
#pragma unroll
        for (int j = 0; j < 4; ++j) {
            float acc = 0.0f;
#pragma unroll
            for (int i2 = 0; i2 < 4; ++i2)
                acc = fmaf(xr[i2], fc1_w[4 * j + i2], acc);
            const float hpre = acc + fc1_b[j];
            h32[j] = (float)tanh((double)hpre);
        }
        float lacc = 0.0f;
#pragma unroll
        for (int j = 0; j < 4; ++j)
            lacc = fmaf(h32[j], picker_w[4 * c + j], lacc);
        const float lg32 = lacc + picker_b[c];
        const float a1 = uu1 + EPSF;
        const float l1 = (float)log((double)a1);
        const float b1 = (-l1) + EPSF;
        const float g1s = -((float)log((double)b1));
        const float a2 = uu2 + EPSF;
        const float l2 = (float)log((double)a2);
        const float b2 = (-l2) + EPSF;
        const float g2s = -((float)log((double)b2));
        const float dd = g1s - g2s;
        const float z32 = lg32 + dd;
        const float e32 = (float)exp((double)(-z32));
        const float den = 1.0f + e32;
        const float s32 = 1.0f / den;
        const float crhard = (s32 >= 0.5f) ? 1.0f : 0.0f;

        soft_o[idx5] = s32;
        hard_o[idx5] = crhard;

        if (crhard != fasthard) {
            float eh[4];
#pragma unroll
            for (int k = 0; k < 4; ++k) {
                float a = eb1[4 * c + k];
#pragma unroll
                for (int j = 0; j < 4; ++j) a += h32[j] * ew1[16 * c + 4 * k + j];
                eh[k] = fmaxf(a, 0.0f);
            }
            float e0 = eb2[2 * c + 0];
            float e1 = eb2[2 * c + 1];
#pragma unroll
            for (int k = 0; k < 4; ++k) {
                e0 += eh[k] * ew2[8 * c + 0 + k];
                e1 += eh[k] * ew2[8 * c + 4 + k];
            }
            const float d = crhard - fasthard;   // +1 or -1
            atomicAdd(&out_o[2u * row + 0], d * e0);
            atomicAdd(&out_o[2u * row + 1], d * e1);
        }
    }
}

extern "C" void kernel_launch(void* const* d_in, const int* in_sizes, int n_in,
                              void* d_out, int out_size, void* d_ws, size_t ws_size,
                              hipStream_t stream) {
    const float* x        = (const float*)d_in[0];
    const float* u1       = (const float*)d_in[1];
    const float* u2       = (const float*)d_in[2];
    const float* fc1_w    = (const float*)d_in[3];
    const float* fc1_b    = (const float*)d_in[4];
    const float* picker_w = (const float*)d_in[5];
    const float* picker_b = (const float*)d_in[6];
    const float* ew1      = (const float*)d_in[7];
    const float* eb1      = (const float*)d_in[8];
    const float* ew2      = (const float*)d_in[9];
    const float* eb2      = (const float*)d_in[10];

    const long long B = in_sizes[0] / 4;        // rows
    float* out  = (float*)d_out;                // [B][2]
    float* hard = out + (size_t)B * 2;          // [B][5]
    float* soft = hard + (size_t)B * 5;         // [B][5]

    unsigned* flag_cnt  = (unsigned*)d_ws;
    unsigned* flag_list = flag_cnt + 1;
    const unsigned flag_cap = (unsigned)(ws_size / 4 - 1);

    hipMemsetAsync(d_ws, 0, 4, stream);         // zero the counter (capturable)

    const int threads = 256;
    const long long nthreads = B / 4;           // 4 rows per thread
    const int blocks = (int)((nthreads + threads - 1) / threads);
    qnet_main<<<blocks, threads, 0, stream>>>(
        x, u1, u2, fc1_w, fc1_b, picker_w, picker_b,
        ew1, eb1, ew2, eb2, out, hard, soft,
        flag_cnt, flag_list, flag_cap);

    qnet_patch<<<128, 256, 0, stream>>>(
        x, u1, u2, fc1_w, fc1_b, picker_w, picker_b,
        ew1, eb1, ew2, eb2, out, hard, soft,
        flag_cnt, flag_list, flag_cap);
}

// Round 10
// 125.264 us; speedup vs baseline: 1.7304x; 1.7304x over previous
//
#include <hip/hip_runtime.h>
#include <math.h>

// Qnet: per-row tiny MLP + gumbel-sigmoid straight-through gates + 5 tiny experts.
//
// Round-9 post-mortem: 4 rows/thread -> VGPR 132 -> 3 waves/SIMD (occ 11%),
// 217us. This kernel is latency-bound; it needs waves. Round-8 config
// (2 rows/thread, VGPR 64, 8 waves/SIMD, 123us) is the sweet spot.
// This round = r8 skeleton + the algebra from r9 that didn't cost registers:
//   - un-divided e-domain: ep = exp(-lg)*t1e; hard = (ep <= t2e);
//     soft = t2e*rcp(t2e+ep)   [saves rcp+mul per gate vs r8]
//   - in-place reg reuse: soft overwrites u1's slot, hard overwrites u2's
//   - tanh(a) = 2*rcp(1+exp(-2a)) - 1  (5 ops, exact limits at +-inf)
//   - ONE flag branch per row (min-margin over 5 gates), entry = row<<5 | mask;
//     patch kernel recomputes all 5 gates of a flagged row bit-exactly
//     (idempotent; adjusts out only where the decision flipped).
// Flag window |ep-t2e| < 1.05e-4*t2e <=> |z_fast| < 1.05e-4; fast-vs-np-f32
// disagreement zone ~3e-5 -> >3x margin. Patch = CR-f32 numpy simulation
// (authority near the boundary).

constexpr float EPSF = 1e-8f;

__device__ __forceinline__ float fast_tanh(float a) {
    // tanh(a) = 2/(1+exp(-2a)) - 1 ; exp overflow/underflow gives correct +-1
    const float e = __expf(-2.0f * a);
    return fmaf(2.0f, __builtin_amdgcn_rcpf(1.0f + e), -1.0f);
}

__global__ __launch_bounds__(256) void qnet_main(
    const float* __restrict__ x,
    const float* __restrict__ u1,
    const float* __restrict__ u2,
    const float* __restrict__ fc1_w,    // [4][4]
    const float* __restrict__ fc1_b,    // [4]
    const float* __restrict__ picker_w, // [5][4]
    const float* __restrict__ picker_b, // [5]
    const float* __restrict__ ew1,      // [5][4][4]
    const float* __restrict__ eb1,      // [5][4]
    const float* __restrict__ ew2,      // [5][2][4]
    const float* __restrict__ eb2,      // [5][2]
    float* __restrict__ out_o,          // [B][2]
    float* __restrict__ hard_o,         // [B][5]
    float* __restrict__ soft_o,         // [B][5]
    unsigned* __restrict__ flag_cnt,    // d_ws[0]
    unsigned* __restrict__ flag_list,   // d_ws[1..]
    unsigned flag_cap)
{
    const unsigned t = blockIdx.x * blockDim.x + threadIdx.x;  // rows 2t, 2t+1

    const float4* x4  = reinterpret_cast<const float4*>(x);
    const float2* u12 = reinterpret_cast<const float2*>(u1);
    const float2* u22 = reinterpret_cast<const float2*>(u2);

    float xr[2][4];
#pragma unroll
    for (int r = 0; r < 2; ++r) {
        float4 v = x4[2u * t + r];
        xr[r][0] = v.x; xr[r][1] = v.y; xr[r][2] = v.z; xr[r][3] = v.w;
    }
    // us1 holds u1, overwritten in place by soft; us2 holds u2 -> hard.
    float us1[10], us2[10];
#pragma unroll
    for (int k = 0; k < 5; ++k) {
        float2 a = u12[5u * t + k];
        us1[2 * k + 0] = a.x; us1[2 * k + 1] = a.y;
        float2 b = u22[5u * t + k];
        us2[2 * k + 0] = b.x; us2[2 * k + 1] = b.y;
    }

    float outf[4];

#pragma unroll
    for (int r = 0; r < 2; ++r) {
        // h = tanh(fc1(x)) — weights at uniform indices (s_load/SGPR)
        float h[4];
#pragma unroll
        for (int j = 0; j < 4; ++j) {
            float a = fc1_b[j];
#pragma unroll
            for (int i = 0; i < 4; ++i) a += xr[r][i] * fc1_w[4 * j + i];
            h[j] = fast_tanh(a);
        }

        float o0 = 0.0f, o1 = 0.0f;
        float rowmin = 1e30f;   // min flag margin over the row's 5 gates

#pragma unroll
        for (int c = 0; c < 5; ++c) {
            float lg = picker_b[c];
#pragma unroll
            for (int j = 0; j < 4; ++j) lg += h[j] * picker_w[4 * c + j];

            const float uu1 = us1[5 * r + c];
            const float uu2 = us2[5 * r + c];
            const float t1e = -__logf(uu1 + EPSF) + EPSF;  // t1 + eps > 0
            const float t2e = -__logf(uu2 + EPSF) + EPSF;
            // e' = exp(-z)*(t2+eps) = exp(-lg)*(t1+eps)   [exact identity]
            const float ep  = __expf(-lg) * t1e;
            const float sft = t2e * __builtin_amdgcn_rcpf(t2e + ep);
            const float hrd = (ep <= t2e) ? 1.0f : 0.0f;

            rowmin = fminf(rowmin, fabsf(ep - t2e) - 1.05e-4f * t2e);

            us1[5 * r + c] = sft;   // in place: u1 -> soft
            us2[5 * r + c] = hrd;   // in place: u2 -> hard

            // expert c: Linear(4,4)->ReLU->Linear(4,2)
            float eh[4];
#pragma unroll
            for (int k = 0; k < 4; ++k) {
                float a = eb1[4 * c + k];
#pragma unroll
                for (int j = 0; j < 4; ++j) a += h[j] * ew1[16 * c + 4 * k + j];
                eh[k] = fmaxf(a, 0.0f);
            }
            float e0 = eb2[2 * c + 0];
            float e1 = eb2[2 * c + 1];
#pragma unroll
            for (int k = 0; k < 4; ++k) {
                e0 += eh[k] * ew2[8 * c + 0 + k];
                e1 += eh[k] * ew2[8 * c + 4 + k];
            }
            o0 += hrd * e0;
            o1 += hrd * e1;
        }

        if (__builtin_expect(rowmin < 0.0f, 0)) {
            unsigned mask = 0;
#pragma unroll
            for (int c = 0; c < 5; ++c)
                mask |= (us2[5 * r + c] != 0.0f) ? (1u << c) : 0u;
            const unsigned slot = atomicAdd(flag_cnt, 1u);
            if (slot < flag_cap)
                flag_list[slot] = ((2u * t + r) << 5) | mask;
        }

        outf[2 * r + 0] = o0;
        outf[2 * r + 1] = o1;
    }

    reinterpret_cast<float4*>(out_o)[t] = make_float4(outf[0], outf[1], outf[2], outf[3]);
    float2* s2 = reinterpret_cast<float2*>(soft_o);
    float2* h2 = reinterpret_cast<float2*>(hard_o);
#pragma unroll
    for (int k = 0; k < 5; ++k) {
        s2[5u * t + k] = make_float2(us1[2 * k + 0], us1[2 * k + 1]);
        h2[5u * t + k] = make_float2(us2[2 * k + 0], us2[2 * k + 1]);
    }
}

// ---- rare patch kernel: bit-exact CR-f32 numpy simulation (authority) ----
// One entry = one flagged ROW (row<<5 | fast-hard mask); recompute all 5 gates.
__global__ __launch_bounds__(256) void qnet_patch(
    const float* __restrict__ x,
    const float* __restrict__ u1,
    const float* __restrict__ u2,
    const float* __restrict__ fc1_w,
    const float* __restrict__ fc1_b,
    const float* __restrict__ picker_w,
    const float* __restrict__ picker_b,
    const float* __restrict__ ew1,
    const float* __restrict__ eb1,
    const float* __restrict__ ew2,
    const float* __restrict__ eb2,
    float* __restrict__ out_o,
    float* __restrict__ hard_o,
    float* __restrict__ soft_o,
    const unsigned* __restrict__ flag_cnt,
    const unsigned* __restrict__ flag_list,
    unsigned flag_cap)
{
    const unsigned n = min(flag_cnt[0], flag_cap);
    const unsigned stride = gridDim.x * blockDim.x;
    for (unsigned i = blockIdx.x * blockDim.x + threadIdx.x; i < n; i += stride) {
        const unsigned e = flag_list[i];
        const unsigned row = e >> 5;
        const unsigned fmask = e & 31u;

        const float4 xv = reinterpret_cast<const float4*>(x)[row];
        const float xr[4] = {xv.x, xv.y, xv.z, xv.w};

        // h: fmaf chain, bias after, CR tanh32 (matches np-f32)
        float h32[4];
#pragma unroll
        for (int j = 0; j < 4; ++j) {
            float acc = 0.0f;
#pragma unroll
            for (int i2 = 0; i2 < 4; ++i2)
                acc = fmaf(xr[i2], fc1_w[4 * j + i2], acc);
            const float hpre = acc + fc1_b[j];
            h32[j] = (float)tanh((double)hpre);
        }

        float dout0 = 0.0f, dout1 = 0.0f;
#pragma unroll
        for (int c = 0; c < 5; ++c) {
            const unsigned idx5 = row * 5u + c;
            const float uu1 = u1[idx5];
            const float uu2 = u2[idx5];

            float lacc = 0.0f;
#pragma unroll
            for (int j = 0; j < 4; ++j)
                lacc = fmaf(h32[j], picker_w[4 * c + j], lacc);
            const float lg32 = lacc + picker_b[c];
            const float a1 = uu1 + EPSF;
            const float l1 = (float)log((double)a1);
            const float b1 = (-l1) + EPSF;
            const float g1s = -((float)log((double)b1));
            const float a2 = uu2 + EPSF;
            const float l2 = (float)log((double)a2);
            const float b2 = (-l2) + EPSF;
            const float g2s = -((float)log((double)b2));
            const float dd = g1s - g2s;
            const float z32 = lg32 + dd;
            const float e32 = (float)exp((double)(-z32));
            const float den = 1.0f + e32;
            const float s32 = 1.0f / den;
            const float crhard = (s32 >= 0.5f) ? 1.0f : 0.0f;
            const float fasthard = ((fmask >> c) & 1u) ? 1.0f : 0.0f;

            soft_o[idx5] = s32;
            hard_o[idx5] = crhard;

            if (crhard != fasthard) {
                float eh[4];
#pragma unroll
                for (int k = 0; k < 4; ++k) {
                    float a = eb1[4 * c + k];
#pragma unroll
                    for (int j = 0; j < 4; ++j) a += h32[j] * ew1[16 * c + 4 * k + j];
                    eh[k] = fmaxf(a, 0.0f);
                }
                float e0 = eb2[2 * c + 0];
                float e1 = eb2[2 * c + 1];
#pragma unroll
                for (int k = 0; k < 4; ++k) {
                    e0 += eh[k] * ew2[8 * c + 0 + k];
                    e1 += eh[k] * ew2[8 * c + 4 + k];
                }
                const float d = crhard - fasthard;   // +1 or -1
                dout0 += d * e0;
                dout1 += d * e1;
            }
        }
        if (dout0 != 0.0f) atomicAdd(&out_o[2u * row + 0], dout0);
        if (dout1 != 0.0f) atomicAdd(&out_o[2u * row + 1], dout1);
    }
}

extern "C" void kernel_launch(void* const* d_in, const int* in_sizes, int n_in,
                              void* d_out, int out_size, void* d_ws, size_t ws_size,
                              hipStream_t stream) {
    const float* x        = (const float*)d_in[0];
    const float* u1       = (const float*)d_in[1];
    const float* u2       = (const float*)d_in[2];
    const float* fc1_w    = (const float*)d_in[3];
    const float* fc1_b    = (const float*)d_in[4];
    const float* picker_w = (const float*)d_in[5];
    const float* picker_b = (const float*)d_in[6];
    const float* ew1      = (const float*)d_in[7];
    const float* eb1      = (const float*)d_in[8];
    const float* ew2      = (const float*)d_in[9];
    const float* eb2      = (const float*)d_in[10];

    const long long B = in_sizes[0] / 4;        // rows
    float* out  = (float*)d_out;                // [B][2]
    float* hard = out + (size_t)B * 2;          // [B][5]
    float* soft = hard + (size_t)B * 5;         // [B][5]

    unsigned* flag_cnt  = (unsigned*)d_ws;
    unsigned* flag_list = flag_cnt + 1;
    const unsigned flag_cap = (unsigned)(ws_size / 4 - 1);

    hipMemsetAsync(d_ws, 0, 4, stream);         // zero the counter (capturable)

    const int threads = 256;
    const long long nthreads = B / 2;           // 2 rows per thread
    const int blocks = (int)((nthreads + threads - 1) / threads);
    qnet_main<<<blocks, threads, 0, stream>>>(
        x, u1, u2, fc1_w, fc1_b, picker_w, picker_b,
        ew1, eb1, ew2, eb2, out, hard, soft,
        flag_cnt, flag_list, flag_cap);

    qnet_patch<<<128, 256, 0, stream>>>(
        x, u1, u2, fc1_w, fc1_b, picker_w, picker_b,
        ew1, eb1, ew2, eb2, out, hard, soft,
        flag_cnt, flag_list, flag_cap);
}